// Round 11
// baseline (159.354 us; speedup 1.0000x reference)
//
#include <hip/hip_runtime.h>

#define Bb 32
#define Nn 4096
#define Dd 256
#define Hh 256
#define NCH 32
#define CHUNK 128

typedef __attribute__((ext_vector_type(8))) _Float16 half8;
typedef __attribute__((ext_vector_type(4))) float f32x4;

__device__ __forceinline__ float fast_tanhf(float x) {
    float e = __expf(2.0f * x);
    return 1.0f - 2.0f / (e + 1.0f);
}

__device__ __forceinline__ half8 cvt8(f32x4 v0, f32x4 v1) {
    half8 h;
    h[0] = (_Float16)v0.x; h[1] = (_Float16)v0.y;
    h[2] = (_Float16)v0.z; h[3] = (_Float16)v0.w;
    h[4] = (_Float16)v1.x; h[5] = (_Float16)v1.y;
    h[6] = (_Float16)v1.z; h[7] = (_Float16)v1.w;
    return h;
}

// ---------------------------------------------------------------------------
// Prep: Wcat = [Wq ; Wk] (H=256 rows, K=512 cols) -> f16 blob, fragment-linear:
// Wf[gs][j][l][e] = (f16) Wcat[j*16+(l&15)][gs*32+(l>>4)*8+e],  gs in [0,16)
// ---------------------------------------------------------------------------
__global__ __launch_bounds__(256) void prep_w_kernel(
    const float* __restrict__ Wq, const float* __restrict__ Wk,
    _Float16* __restrict__ Wf)
{
    const int g = blockIdx.x * 256 + threadIdx.x;      // [0, 16384)
    const int s = g >> 10;
    const int j = (g >> 6) & 15;
    const int l = g & 63;
    const int n = j * 16 + (l & 15);
    const int k = s * 32 + (l >> 4) * 8;
    const float* src = (k < 256) ? (Wq + n * 256 + k) : (Wk + n * 256 + (k - 256));
    const f32x4 v0 = *(const f32x4*)src;
    const f32x4 v1 = *(const f32x4*)(src + 4);
    *(half8*)&Wf[(size_t)g * 8] = cvt8(v0, v1);
}

// ---------------------------------------------------------------------------
// Scores, ONE-SHOT A-tile. Block = 64 rows x 256 h, 4 waves; wave w owns cols
// [64w,64w+64): m=4 x n=4 tiles of 16x16x32 f16 MFMA.
// Phase 1 (staging): whole A-tile (64 rows x K=512, f16 = 64 KB) into LDS,
//   frag-linear: Af[((gs*4+m)*64 + lane)*8] = A[m*16+(lane&15)][gs*32+(lane>>4)*8].
//   Wave w stages k-chunk [w*128, w*128+128) for all 64 rows (lane = row).
// Phase 2 (after ONE barrier): 16 gs-steps of {4 ds_read_b128 (lane-contig,
//   conflict-free) + 4 B L2-loads (depth-2 named-reg pipeline) + 16 MFMA},
//   NO barriers -> compiler pipelines loads freely; 2 blocks/CU overlap
//   (one staging from HBM while the other computes from L2).
// ---------------------------------------------------------------------------
__global__ __launch_bounds__(256, 2) void scores_oneshot_kernel(
    const float* __restrict__ Q, const float* __restrict__ Kmat,
    const _Float16* __restrict__ Wf,
    const float* __restrict__ Wv, float* __restrict__ scores)
{
    __shared__ _Float16 Af[64 * 512];   // 64 KB
    __shared__ float red[4][64];

    const int tid = threadIdx.x;
    const int lane = tid & 63;
    const int wave = tid >> 6;
    const size_t row0 = (size_t)blockIdx.x * 64;

    f32x4 acc[4][4];
#pragma unroll
    for (int m = 0; m < 4; ++m)
#pragma unroll
        for (int n = 0; n < 4; ++n) acc[m][n] = (f32x4){0.f, 0.f, 0.f, 0.f};

    float wv[4];
#pragma unroll
    for (int n = 0; n < 4; ++n) wv[n] = Wv[wave * 64 + n * 16 + (lane & 15)];

    half8 BA[4], BB[4];
    auto loadB_A = [&](int gs) {
#pragma unroll
        for (int n = 0; n < 4; ++n)
            BA[n] = *(const half8*)(Wf + ((size_t)(gs * 16 + wave * 4 + n) * 64 + lane) * 8);
    };
    auto loadB_B = [&](int gs) {
#pragma unroll
        for (int n = 0; n < 4; ++n)
            BB[n] = *(const half8*)(Wf + ((size_t)(gs * 16 + wave * 4 + n) * 64 + lane) * 8);
    };

    // ---- Phase 1: stage A. wave w: rows = lane, k in [w*128, w*128+128).
    loadB_A(0);   // B step-0 prefetch rides along; drained by the barrier
    {
        const float* src = (wave < 2)
            ? (Q    + (row0 + lane) * Dd + wave * 128)
            : (Kmat + (row0 + lane) * Dd + (wave - 2) * 128);
        const int m = lane >> 4;
        const int rl = lane & 15;
#pragma unroll
        for (int g = 0; g < 16; ++g) {
            const f32x4 v0 = *(const f32x4*)(src + g * 8);
            const f32x4 v1 = *(const f32x4*)(src + g * 8 + 4);
            const int gs = wave * 4 + (g >> 2);
            const int sub = g & 3;
            *(half8*)&Af[((gs * 4 + m) * 64 + sub * 16 + rl) * 8] = cvt8(v0, v1);
        }
    }
    __syncthreads();

    // ---- Phase 2: barrier-free MFMA loop, B depth-2 pipelined.
    __builtin_amdgcn_s_setprio(1);
#pragma unroll
    for (int g2 = 0; g2 < 8; ++g2) {
        const int gs = 2 * g2;
        loadB_B(gs + 1);
#pragma unroll
        for (int m = 0; m < 4; ++m) {
            const half8 a = *(const half8*)&Af[((gs * 4 + m) * 64 + lane) * 8];
#pragma unroll
            for (int n = 0; n < 4; ++n)
                acc[m][n] = __builtin_amdgcn_mfma_f32_16x16x32_f16(a, BA[n], acc[m][n], 0, 0, 0);
        }
        if (gs + 2 < 16) loadB_A(gs + 2);
#pragma unroll
        for (int m = 0; m < 4; ++m) {
            const half8 a = *(const half8*)&Af[(((gs + 1) * 4 + m) * 64 + lane) * 8];
#pragma unroll
            for (int n = 0; n < 4; ++n)
                acc[m][n] = __builtin_amdgcn_mfma_f32_16x16x32_f16(a, BB[n], acc[m][n], 0, 0, 0);
        }
    }
    __builtin_amdgcn_s_setprio(0);

    // Epilogue: score_row += Wv[col]*tanh(acc). C/D: col = lane&15,
    // row = m*16+(lane>>4)*4+r. Fixed-order reduce -> deterministic.
    const int q = lane >> 4;
    float rp[4][4];
#pragma unroll
    for (int m = 0; m < 4; ++m)
#pragma unroll
        for (int r = 0; r < 4; ++r) {
            float v = 0.f;
#pragma unroll
            for (int n = 0; n < 4; ++n)
                v += wv[n] * fast_tanhf(acc[m][n][r]);
            rp[m][r] = v;
        }
#pragma unroll
    for (int mask = 1; mask <= 8; mask <<= 1)
#pragma unroll
        for (int m = 0; m < 4; ++m)
#pragma unroll
            for (int r = 0; r < 4; ++r)
                rp[m][r] += __shfl_xor(rp[m][r], mask, 64);

    if ((lane & 15) == 0) {
#pragma unroll
        for (int m = 0; m < 4; ++m)
#pragma unroll
            for (int r = 0; r < 4; ++r)
                red[wave][m * 16 + q * 4 + r] = rp[m][r];
    }
    __syncthreads();
    if (tid < 64)
        scores[row0 + tid] = (red[0][tid] + red[1][tid]) + (red[2][tid] + red[3][tid]);
}

// ---------------------------------------------------------------------------
// Per-b max + argmax + sum(exp). Argmax protected by f64 safety net:
// candidates within tau of max are recomputed exactly (f64 accumulation);
// pick by (exact score, lowest index). Deterministic: candidate SET is
// data-determined and the (value,index) argmax is order-independent.
// ---------------------------------------------------------------------------
#define MAXC 64
__global__ __launch_bounds__(256) void softmax_reduce_kernel(
    const float* __restrict__ scores,
    const float* __restrict__ Qg, const float* __restrict__ Kg,
    const float* __restrict__ Wq, const float* __restrict__ Wk,
    const float* __restrict__ Wv,
    float* __restrict__ mbuf, float* __restrict__ zbuf, float* __restrict__ out)
{
    __shared__ float sv[256];
    __shared__ int si[256];
    __shared__ double dred[256];
    __shared__ int cand[MAXC];
    __shared__ int cnt;
    const int b = blockIdx.x;
    const int tid = threadIdx.x;
    const float* sc = scores + (size_t)b * Nn;

    float best = -1e30f; int bi = 0;
    for (int j = 0; j < Nn / 256; ++j) {
        const int n = tid + j * 256;
        const float v = sc[n];
        if (v > best) { best = v; bi = n; }
    }
    sv[tid] = best; si[tid] = bi;
    __syncthreads();
    for (int off = 128; off > 0; off >>= 1) {
        if (tid < off) {
            const float v2 = sv[tid + off]; const int i2 = si[tid + off];
            if (v2 > sv[tid] || (v2 == sv[tid] && i2 < si[tid])) { sv[tid] = v2; si[tid] = i2; }
        }
        __syncthreads();
    }
    const float m = sv[0];
    int amax = si[0];
    __syncthreads();

    float ssum = 0.f;
    for (int j = 0; j < Nn / 256; ++j) ssum += __expf(sc[tid + j * 256] - m);
    sv[tid] = ssum;
    __syncthreads();
    for (int off = 128; off > 0; off >>= 1) {
        if (tid < off) sv[tid] += sv[tid + off];
        __syncthreads();
    }
    const float Z = sv[0];
    __syncthreads();

    if (tid == 0) cnt = 0;
    __syncthreads();
    const float tau = 0.02f;    // >> 5-sigma f16-GEMM score error (~1.4e-3 std)
    for (int j = 0; j < Nn / 256; ++j) {
        const int n = tid + j * 256;
        if (sc[n] >= m - tau) {
            const int p = atomicAdd(&cnt, 1);
            if (p < MAXC) cand[p] = n;
        }
    }
    __syncthreads();
    const int ncand = (cnt < MAXC) ? cnt : MAXC;
    if (ncand > 1) {
        double bestv = -1e300; int besti = 0x7fffffff;
        for (int c = 0; c < ncand; ++c) {
            const int n = cand[c];
            const float* qr = Qg + ((size_t)b * Nn + n) * Dd;
            const float* kr = Kg + ((size_t)b * Nn + n) * Dd;
            const float* wqr = Wq + tid * Dd;
            const float* wkr = Wk + tid * Dd;
            double accd = 0.0;
            for (int k2 = 0; k2 < Dd; ++k2)
                accd += (double)qr[k2] * (double)wqr[k2] + (double)kr[k2] * (double)wkr[k2];
            dred[tid] = (double)Wv[tid] * tanh(accd);
            __syncthreads();
            for (int off = 128; off > 0; off >>= 1) {
                if (tid < off) dred[tid] += dred[tid + off];
                __syncthreads();
            }
            const double s_c = dred[0];
            __syncthreads();
            if (s_c > bestv || (s_c == bestv && n < besti)) { bestv = s_c; besti = n; }
        }
        amax = besti;
    }

    if (tid == 0) {
        mbuf[b] = m;
        zbuf[b] = Z;
        out[(size_t)Bb * Dd + b] = (float)amax;
    }
}

// ---------------------------------------------------------------------------
// Partial out over n-chunks (no atomics; fixed-order accumulation)
// ---------------------------------------------------------------------------
__global__ __launch_bounds__(256) void partial_kernel(
    const float* __restrict__ V, const float* __restrict__ scores,
    const float* __restrict__ mbuf, float* __restrict__ part)
{
    __shared__ float e[CHUNK];
    const int c = blockIdx.x;
    const int b = blockIdx.y;
    const int tid = threadIdx.x;
    const float m = mbuf[b];
    if (tid < CHUNK)
        e[tid] = __expf(scores[(size_t)b * Nn + (size_t)c * CHUNK + tid] - m);
    __syncthreads();

    const float* vp = V + ((size_t)b * Nn + (size_t)c * CHUNK) * Dd + tid;
    float a0 = 0.f, a1 = 0.f, a2 = 0.f, a3 = 0.f;
    for (int n = 0; n < CHUNK; n += 4) {
        a0 = fmaf(e[n + 0], vp[(size_t)(n + 0) * Dd], a0);
        a1 = fmaf(e[n + 1], vp[(size_t)(n + 1) * Dd], a1);
        a2 = fmaf(e[n + 2], vp[(size_t)(n + 2) * Dd], a2);
        a3 = fmaf(e[n + 3], vp[(size_t)(n + 3) * Dd], a3);
    }
    part[((size_t)b * NCH + c) * Dd + tid] = ((a0 + a1) + (a2 + a3));
}

__global__ __launch_bounds__(256) void finalize_kernel(
    const float* __restrict__ part, const float* __restrict__ zbuf,
    float* __restrict__ out)
{
    const int b = blockIdx.x;
    const int tid = threadIdx.x;
    float s = 0.f;
#pragma unroll
    for (int c = 0; c < NCH; ++c) s += part[((size_t)b * NCH + c) * Dd + tid];
    out[(size_t)b * Dd + tid] = s / zbuf[b];
}

extern "C" void kernel_launch(void* const* d_in, const int* in_sizes, int n_in,
                              void* d_out, int out_size, void* d_ws, size_t ws_size,
                              hipStream_t stream) {
    const float* Q  = (const float*)d_in[0];
    const float* K  = (const float*)d_in[1];
    const float* V  = (const float*)d_in[2];
    const float* Wq = (const float*)d_in[3];
    const float* Wk = (const float*)d_in[4];
    const float* Wv = (const float*)d_in[5];
    float* out = (float*)d_out;

    // ws layout (bytes): Wf[256K] | scores[512K] | m[128] | z[128] | part[1M]
    char* wsb = (char*)d_ws;
    _Float16* Wf  = (_Float16*)(wsb);
    float* scores = (float*)(wsb + 262144);
    float* mbuf   = (float*)(wsb + 786432);
    float* zbuf   = (float*)(wsb + 786432 + 128);
    float* part   = (float*)(wsb + 786432 + 256);

    prep_w_kernel<<<dim3(64), dim3(256), 0, stream>>>(Wq, Wk, Wf);
    scores_oneshot_kernel<<<dim3((Bb * Nn) / 64), dim3(256), 0, stream>>>(Q, K, Wf, Wv, scores);
    softmax_reduce_kernel<<<dim3(Bb), dim3(256), 0, stream>>>(scores, Q, K, Wq, Wk, Wv, mbuf, zbuf, out);
    partial_kernel<<<dim3(NCH, Bb), dim3(256), 0, stream>>>(V, scores, mbuf, part);
    finalize_kernel<<<dim3(Bb), dim3(256), 0, stream>>>(part, zbuf, out);
}